// Round 20
// baseline (434.930 us; speedup 1.0000x reference)
//
#include <hip/hip_runtime.h>

#define NT 8192      // tokens = B*S
#define DIM 1024     // D
#define FDIM 4096    // F
#define NEXP 8       // experts

typedef __attribute__((ext_vector_type(8))) short bfx8;   // 8 bf16 (4 VGPRs)
typedef __attribute__((ext_vector_type(4))) float fx4;    // MFMA accumulator

__device__ __forceinline__ unsigned short f2bf(float f) {
  union { float f; unsigned u; } v; v.f = f;
  unsigned u = v.u;
  unsigned r = u + 0x7FFFu + ((u >> 16) & 1u);   // round-to-nearest-even
  return (unsigned short)(r >> 16);
}

__device__ __forceinline__ void gload16(const void* g, void* l) {
  __builtin_amdgcn_global_load_lds(
      (const __attribute__((address_space(1))) unsigned int*)g,
      (__attribute__((address_space(3))) unsigned int*)l, 16, 0, 0);
}

// ---- 64x64 transpose tile, two-key swizzle (R18/R19-proven) ----
__device__ __forceinline__ void tr64(
    const float* __restrict__ src, unsigned short* __restrict__ dst,
    int R, int C, int r0, int c0, float* T, int tid)
{
  const int lane = tid & 63, wv = tid >> 6;
  const int rw = wv * 4 + (lane >> 4);          // row within each 16-row group
#pragma unroll
  for (int i = 0; i < 4; ++i) {
    const int cb = (lane & 15) ^ (rw & 7) ^ (i * 2) ^ (rw >> 3);
    gload16(src + (size_t)(r0 + i * 16 + rw) * C + c0 + cb * 4,
            &T[(i * 16 + wv * 4) * 64]);
  }
  __syncthreads();
  const int q = tid & 7, cy = tid >> 3;
#pragma unroll
  for (int it = 0; it < 2; ++it) {
    const int c = cy + it * 32;
    unsigned short o[8];
#pragma unroll
    for (int u = 0; u < 8; ++u)
      o[u] = f2bf(T[(q * 8 + u) * 64 + ((((c >> 2) ^ u ^ q) << 2) | (c & 3))]);
    *(uint4*)(dst + (size_t)(c0 + c) * R + r0 + q * 8) = *(const uint4*)o;
  }
}

// ---------------- zero counters ----------------
__global__ void k_zero(int* __restrict__ counts) {
  if (threadIdx.x < NEXP) counts[threadIdx.x] = 0;
}

// ---------------- P1: routing+LN | w1^T first half (f < 2048) ----------------
__global__ __launch_bounds__(256) void k_pre(
    const float* __restrict__ x, const float* __restrict__ cent,
    const float* __restrict__ g, const float* __restrict__ b,
    const float* __restrict__ w1,
    int* __restrict__ eid, float* __restrict__ alpha, int* __restrict__ counts,
    unsigned short* __restrict__ xln, unsigned short* __restrict__ w1t)
{
  __shared__ float T[64 * 64];
  __shared__ float part[4][NEXP], ps[4], pss[4];
  __shared__ float sMu, sRstd;
  __shared__ int sE;
  const int bid = blockIdx.x, tid = threadIdx.x;

  if (bid < NT) {
    const int t = bid;
    const float4 xv = ((const float4*)(x + (size_t)t * DIM))[tid];
    float acc[NEXP];
#pragma unroll
    for (int e = 0; e < NEXP; ++e) {
      const float4 cv = ((const float4*)(cent + (size_t)e * DIM))[tid];
      acc[e] = xv.x * cv.x + xv.y * cv.y + xv.z * cv.z + xv.w * cv.w;
    }
    float s = xv.x + xv.y + xv.z + xv.w;
    float ss = xv.x * xv.x + xv.y * xv.y + xv.z * xv.z + xv.w * xv.w;
#pragma unroll
    for (int off = 32; off > 0; off >>= 1) {
#pragma unroll
      for (int e = 0; e < NEXP; ++e) acc[e] += __shfl_down(acc[e], off);
      s += __shfl_down(s, off); ss += __shfl_down(ss, off);
    }
    const int lane = tid & 63, w = tid >> 6;
    if (lane == 0) {
#pragma unroll
      for (int e = 0; e < NEXP; ++e) part[w][e] = acc[e];
      ps[w] = s; pss[w] = ss;
    }
    __syncthreads();
    if (tid == 0) {
      int best = 0; float bv = -1e30f;
#pragma unroll
      for (int e = 0; e < NEXP; ++e) {
        float v = part[0][e] + part[1][e] + part[2][e] + part[3][e];
        if (v > bv) { bv = v; best = e; }   // strict >: first max (matches argmax)
      }
      eid[t] = best;
      alpha[t] = 1.0f / (1.0f + expf(-bv));
      atomicAdd(&counts[best], 1);
      const float sum = ps[0] + ps[1] + ps[2] + ps[3];
      const float sq  = pss[0] + pss[1] + pss[2] + pss[3];
      const float mu = sum * (1.0f / DIM);
      const float var = sq * (1.0f / DIM) - mu * mu;
      sE = best; sMu = mu; sRstd = rsqrtf(var + 1e-5f);
    }
    __syncthreads();
    const int e = sE;
    const float mu = sMu, rstd = sRstd;
    const float4 gv = ((const float4*)(g + (size_t)e * DIM))[tid];
    const float4 bv4 = ((const float4*)(b + (size_t)e * DIM))[tid];
    ushort4 o;
    o.x = f2bf((xv.x - mu) * rstd * gv.x + bv4.x);
    o.y = f2bf((xv.y - mu) * rstd * gv.y + bv4.y);
    o.z = f2bf((xv.z - mu) * rstd * gv.z + bv4.z);
    o.w = f2bf((xv.w - mu) * rstd * gv.w + bv4.w);
    ((ushort4*)(xln + (size_t)t * DIM))[tid] = o;
  } else {
    const int i = bid - NT;                   // [0,4096): c-tiles 0..31 (f<2048)
    const int e = i >> 9, rem = i & 511;
    tr64(w1 + (size_t)e * DIM * FDIM, w1t + (size_t)e * DIM * FDIM,
         DIM, FDIM, (rem & 15) * 64, (rem >> 4) * 64, T, tid);
  }
}

// ---------------- exclusive scan of 8 counts ----------------
__global__ void k_scan(const int* __restrict__ counts, int* __restrict__ bs, int* __restrict__ cur) {
  if (threadIdx.x == 0) {
    int s = 0;
    for (int e = 0; e < NEXP; ++e) { bs[e] = s; cur[e] = s; s += counts[e]; }
  }
}

// ---------------- build pos -> token map (index-only counting sort) ----------------
__global__ void k_rowtok(const int* __restrict__ eid, int* __restrict__ cur,
                         int* __restrict__ row_tok) {
  const int t = blockIdx.x * 256 + threadIdx.x;
  const int e = eid[t];
  const int pos = atomicAdd(&cur[e], 1);
  row_tok[pos] = t;
}

// ---------------- GEMM1 half (16 n-panels) + appended transpose blocks ----------
// bids [0,8192): grouped GEMM (e=bid&7==XCD, m fastest), n0=(npoff+l/64)*128;
// bids >= 8192: transpose tiles. tw2=0 -> w1 second half (c-tiles 32..63);
// tw2=1 -> w2 full (8192 tiles).
__global__ __launch_bounds__(256) void k_gemm1(
    const unsigned short* __restrict__ A,
    const unsigned short* __restrict__ Bt,
    const float* __restrict__ bias,
    const int* __restrict__ bs, const int* __restrict__ counts,
    unsigned short* __restrict__ Hout,
    const int* __restrict__ row_tok,
    int npoff, int tw2,
    const float* __restrict__ wsrc, unsigned short* __restrict__ wdst)
{
  __shared__ __align__(16) char smem[32 * 132 * 4];
  const int tid = threadIdx.x;

  if (blockIdx.x >= 8192) {
    const int i = blockIdx.x - 8192;
    if (!tw2) {           // w1 second half: c-tiles 32..63
      const int e = i >> 9, rem = i & 511;
      tr64(wsrc + (size_t)e * DIM * FDIM, wdst + (size_t)e * DIM * FDIM,
           DIM, FDIM, (rem & 15) * 64, (32 + (rem >> 4)) * 64, (float*)smem, tid);
    } else {              // w2 full: 64 r-tiles x 16 c-tiles per expert
      const int e = i >> 10, rem = i & 1023;
      tr64(wsrc + (size_t)e * FDIM * DIM, wdst + (size_t)e * FDIM * DIM,
           FDIM, DIM, (rem >> 4) * 64, (rem & 15) * 64, (float*)smem, tid);
    }
    return;
  }

  unsigned short* lA = (unsigned short*)smem;
  unsigned short* lB = (unsigned short*)(smem + 8192);
  float* Lf = (float*)smem;

  const int MB = NT / 128;                     // 64
  const int bid = blockIdx.x;
  const int e = bid & 7;
  const int l = bid >> 3;
  const int m0 = (l % MB) * 128;               // m fastest
  const int cnt = counts[e];
  if (m0 >= cnt) return;
  const int n0 = (npoff + l / MB) * 128;
  const int rbase = bs[e];

  const int lane = tid & 63, wv = tid >> 6;
  const int wm = (wv >> 1) * 64, wn = (wv & 1) * 64;
  const int lr = lane & 15, lg = lane >> 4;

  fx4 acc[4][4] = {};

  const unsigned short* Bte = Bt + (size_t)e * (size_t)FDIM * DIM;

  const unsigned short* aP[2];
  const unsigned short* bP[2];
#pragma unroll
  for (int p = 0; p < 2; ++p) {
    const int g = p * 256 + tid;
    const int row = g >> 2, kq = (g & 3) * 8;
    int ar = rbase + m0 + row;
    ar = ar < NT ? ar : NT - 1;               // clamp: pad rows masked at epilogue
    const int tok = row_tok[ar];              // gather: xln is natural order
    aP[p] = A + (size_t)tok * DIM + kq;
    bP[p] = Bte + (size_t)(n0 + row) * DIM + kq;
  }

  for (int k0 = 0; k0 < DIM; k0 += 32) {
    gload16(aP[0] + k0, &lA[(0 * 4 + wv) * 512]);
    gload16(aP[1] + k0, &lA[(1 * 4 + wv) * 512]);
    gload16(bP[0] + k0, &lB[(0 * 4 + wv) * 512]);
    gload16(bP[1] + k0, &lB[(1 * 4 + wv) * 512]);
    __syncthreads();                          // compiler-managed vmcnt drain
    bfx8 bf[4];
#pragma unroll
    for (int j = 0; j < 4; ++j)
      bf[j] = *(const bfx8*)(&lB[(wn + j * 16 + lr) * 32 + lg * 8]);
#pragma unroll
    for (int i = 0; i < 4; ++i) {
      const bfx8 af = *(const bfx8*)(&lA[(wm + i * 16 + lr) * 32 + lg * 8]);
#pragma unroll
      for (int j = 0; j < 4; ++j)
        acc[i][j] = __builtin_amdgcn_mfma_f32_16x16x32_bf16(af, bf[j], acc[i][j], 0, 0, 0);
    }
    __syncthreads();
  }

  const float* be = bias + (size_t)e * FDIM;
  float bcol[4];
#pragma unroll
  for (int j = 0; j < 4; ++j) bcol[j] = be[n0 + wn + j * 16 + lr];

#pragma unroll
  for (int i = 0; i < 4; ++i) {
    __syncthreads();                          // protect LDS reuse
#pragma unroll
    for (int r2 = 0; r2 < 4; ++r2) {
      const int rowp = (wv >> 1) * 16 + lg * 4 + r2;    // 0..31
#pragma unroll
      for (int j = 0; j < 4; ++j) {
        float v = acc[i][j][r2] + bcol[j];
        Lf[rowp * 132 + wn + j * 16 + lr] = v > 0.f ? v : 0.f;
      }
    }
    __syncthreads();
#pragma unroll
    for (int s = 0; s < 2; ++s) {
      const int tsk = tid + 256 * s;                  // 0..511
      const int rr = tsk >> 4, cg = tsk & 15;
      const int ra = i * 16 + ((rr >> 4) << 6) + (rr & 15);
      if (m0 + ra < cnt) {
        const float4 a = *(const float4*)&Lf[rr * 132 + cg * 8];
        const float4 b = *(const float4*)&Lf[rr * 132 + cg * 8 + 4];
        unsigned short o[8] = { f2bf(a.x), f2bf(a.y), f2bf(a.z), f2bf(a.w),
                                f2bf(b.x), f2bf(b.y), f2bf(b.z), f2bf(b.w) };
        *(uint4*)(Hout + (size_t)(rbase + m0 + ra) * FDIM + n0 + cg * 8) =
            *(const uint4*)o;
      }
    }
  }
}

// ---------------- GEMM2: R17/R19 byte-identical ----------------
__global__ __launch_bounds__(256) void k_gemm2(
    const unsigned short* __restrict__ A,
    const unsigned short* __restrict__ Bt,
    const float* __restrict__ bias,
    const int* __restrict__ bs, const int* __restrict__ counts,
    const int* __restrict__ row_tok, const float* __restrict__ alpha,
    const float* __restrict__ xin, float* __restrict__ out)
{
  const int MB = NT / 128;
  const int bid = blockIdx.x;
  const int e = bid & 7;
  const int l = bid >> 3;
  const int m0 = (l % MB) * 128;               // m fastest
  const int cnt = counts[e];
  if (m0 >= cnt) return;
  const int n0 = (l / MB) * 128;
  const int rbase = bs[e];

  __shared__ __align__(16) char smem[32 * 132 * 4];
  unsigned short* lA = (unsigned short*)smem;
  unsigned short* lB = (unsigned short*)(smem + 8192);
  float* Lf = (float*)smem;

  const int tid = threadIdx.x;
  const int lane = tid & 63, wv = tid >> 6;
  const int wm = (wv >> 1) * 64, wn = (wv & 1) * 64;
  const int lr = lane & 15, lg = lane >> 4;

  fx4 acc[4][4] = {};

  const unsigned short* Bte = Bt + (size_t)e * (size_t)DIM * FDIM;

  const unsigned short* aP[2];
  const unsigned short* bP[2];
#pragma unroll
  for (int p = 0; p < 2; ++p) {
    const int g = p * 256 + tid;
    const int row = g >> 2, kq = (g & 3) * 8;
    int ar = rbase + m0 + row;
    ar = ar < NT ? ar : NT - 1;               // clamp: pad rows masked at epilogue
    aP[p] = A + (size_t)ar * FDIM + kq;       // hbuf is sorted order
    bP[p] = Bte + (size_t)(n0 + row) * FDIM + kq;
  }

  for (int k0 = 0; k0 < FDIM; k0 += 32) {
    gload16(aP[0] + k0, &lA[(0 * 4 + wv) * 512]);
    gload16(aP[1] + k0, &lA[(1 * 4 + wv) * 512]);
    gload16(bP[0] + k0, &lB[(0 * 4 + wv) * 512]);
    gload16(bP[1] + k0, &lB[(1 * 4 + wv) * 512]);
    __syncthreads();                          // compiler-managed vmcnt drain
    bfx8 bf[4];
#pragma unroll
    for (int j = 0; j < 4; ++j)
      bf[j] = *(const bfx8*)(&lB[(wn + j * 16 + lr) * 32 + lg * 8]);
#pragma unroll
    for (int i = 0; i < 4; ++i) {
      const bfx8 af = *(const bfx8*)(&lA[(wm + i * 16 + lr) * 32 + lg * 8]);
#pragma unroll
      for (int j = 0; j < 4; ++j)
        acc[i][j] = __builtin_amdgcn_mfma_f32_16x16x32_bf16(af, bf[j], acc[i][j], 0, 0, 0);
    }
    __syncthreads();
  }

  const float* be = bias + (size_t)e * DIM;
  float bcol[4];
#pragma unroll
  for (int j = 0; j < 4; ++j) bcol[j] = be[n0 + wn + j * 16 + lr];

#pragma unroll
  for (int i = 0; i < 4; ++i) {
    __syncthreads();                          // protect LDS reuse
#pragma unroll
    for (int r2 = 0; r2 < 4; ++r2) {
      const int rowp = (wv >> 1) * 16 + lg * 4 + r2;    // 0..31
#pragma unroll
      for (int j = 0; j < 4; ++j)
        Lf[rowp * 132 + wn + j * 16 + lr] = acc[i][j][r2] + bcol[j];
    }
    __syncthreads();
#pragma unroll
    for (int s = 0; s < 4; ++s) {
      const int tsk = tid + 256 * s;                  // 0..1023
      const int rr = tsk >> 5, c4 = tsk & 31;
      const int ra = i * 16 + ((rr >> 4) << 6) + (rr & 15);
      if (m0 + ra < cnt) {
        const int tok = row_tok[rbase + m0 + ra];
        const float al = alpha[tok];
        const float4 v = *(const float4*)&Lf[rr * 132 + c4 * 4];
        const float4 xr = *(const float4*)(xin + (size_t)tok * DIM + n0 + c4 * 4);
        float4 o;
        o.x = xr.x + al * v.x;
        o.y = xr.y + al * v.y;
        o.z = xr.z + al * v.z;
        o.w = xr.w + al * v.w;
        *(float4*)(out + (size_t)tok * DIM + n0 + c4 * 4) = o;
      }
    }
  }
}

extern "C" void kernel_launch(void* const* d_in, const int* in_sizes, int n_in,
                              void* d_out, int out_size, void* d_ws, size_t ws_size,
                              hipStream_t stream)
{
  const float* x    = (const float*)d_in[0];
  const float* cent = (const float*)d_in[1];
  const float* ln_g = (const float*)d_in[2];
  const float* ln_b = (const float*)d_in[3];
  const float* w1   = (const float*)d_in[4];
  const float* b1   = (const float*)d_in[5];
  const float* w2   = (const float*)d_in[6];
  const float* b2   = (const float*)d_in[7];
  float* out = (float*)d_out;

  char* ws = (char*)d_ws;
  unsigned short* xln  = (unsigned short*)(ws);                          // 16 MB (natural order)
  unsigned short* hbuf = (unsigned short*)(ws + (16ull << 20));          // 64 MB (sorted order)
  unsigned short* w1t  = (unsigned short*)(ws + (80ull << 20));          // 64 MB [E][F][D]
  unsigned short* w2t  = (unsigned short*)(ws + (144ull << 20));         // 64 MB [E][D][F]
  char* tail = ws + (208ull << 20);
  int*    eid    = (int*)(tail);
  float*  alpha  = (float*)(tail + 32768);
  int*    rowtok = (int*)(tail + 65536);
  int*    counts = (int*)(tail + 98304);
  int*    basep  = counts + 16;
  int*    cur    = counts + 32;

  k_zero<<<1, 64, 0, stream>>>(counts);
  // P1: routing + w1t first half (f < 2048)
  k_pre<<<NT + 4096, 256, 0, stream>>>(
      x, cent, ln_g, ln_b, w1, eid, alpha, counts, xln, w1t);
  k_scan<<<1, 1, 0, stream>>>(counts, basep, cur);
  k_rowtok<<<NT / 256, 256, 0, stream>>>(eid, cur, rowtok);
  // P2: GEMM1 panels 0..15 + w1t second half appended
  k_gemm1<<<8192 + 4096, 256, 0, stream>>>(
      xln, w1t, b1, basep, counts, hbuf, rowtok, 0, 0, w1, w1t);
  // P3: GEMM1 panels 16..31 + w2t appended
  k_gemm1<<<8192 + 8192, 256, 0, stream>>>(
      xln, w1t, b1, basep, counts, hbuf, rowtok, 16, 1, w2, w2t);
  // P4: GEMM2
  k_gemm2<<<NEXP * (NT / 128) * (DIM / 128), 256, 0, stream>>>(
      hbuf, w2t, b2, basep, counts, rowtok, alpha, x, out);
}

// Round 21
// 427.319 us; speedup vs baseline: 1.0178x; 1.0178x over previous
//
#include <hip/hip_runtime.h>

#define NT 8192      // tokens = B*S
#define DIM 1024     // D
#define FDIM 4096    // F
#define NEXP 8       // experts

typedef __attribute__((ext_vector_type(8))) short bfx8;   // 8 bf16 (4 VGPRs)
typedef __attribute__((ext_vector_type(4))) float fx4;    // MFMA accumulator

__device__ __forceinline__ unsigned short f2bf(float f) {
  union { float f; unsigned u; } v; v.f = f;
  unsigned u = v.u;
  unsigned r = u + 0x7FFFu + ((u >> 16) & 1u);   // round-to-nearest-even
  return (unsigned short)(r >> 16);
}

__device__ __forceinline__ void gload16(const void* g, void* l) {
  __builtin_amdgcn_global_load_lds(
      (const __attribute__((address_space(1))) unsigned int*)g,
      (__attribute__((address_space(3))) unsigned int*)l, 16, 0, 0);
}

// ---- 64x64 transpose tile, two-key swizzle (R18/R19-proven) ----
// Split into issue (DMA) and process (read+store) so callers can pipeline.
__device__ __forceinline__ void tr64_issue(
    const float* __restrict__ src, int C, int r0, int c0, float* T, int tid)
{
  const int lane = tid & 63, wv = tid >> 6;
  const int rw = wv * 4 + (lane >> 4);          // row within each 16-row group
#pragma unroll
  for (int i = 0; i < 4; ++i) {
    const int cb = (lane & 15) ^ (rw & 7) ^ (i * 2) ^ (rw >> 3);
    gload16(src + (size_t)(r0 + i * 16 + rw) * C + c0 + cb * 4,
            &T[(i * 16 + wv * 4) * 64]);
  }
}

__device__ __forceinline__ void tr64_process(
    unsigned short* __restrict__ dst, int R, int r0, int c0, const float* T, int tid)
{
  const int q = tid & 7, cy = tid >> 3;
#pragma unroll
  for (int it = 0; it < 2; ++it) {
    const int c = cy + it * 32;
    unsigned short o[8];
#pragma unroll
    for (int u = 0; u < 8; ++u)
      o[u] = f2bf(T[(q * 8 + u) * 64 + ((((c >> 2) ^ u ^ q) << 2) | (c & 3))]);
    *(uint4*)(dst + (size_t)(c0 + c) * R + r0 + q * 8) = *(const uint4*)o;
  }
}

// ---------------- zero counters ----------------
__global__ void k_zero(int* __restrict__ counts) {
  if (threadIdx.x < NEXP) counts[threadIdx.x] = 0;
}

// ---------------- P1: routing+LN | w1^T (2 tiles per block, pipelined DMA) ----
// bid [0,NT): routing+LN; [NT,NT+4096): w1t tile-pairs (adjacent c-tiles,
// both tiles' DMAs issued before one barrier -> latency paid once per pair).
__global__ __launch_bounds__(256) void k_pre(
    const float* __restrict__ x, const float* __restrict__ cent,
    const float* __restrict__ g, const float* __restrict__ b,
    const float* __restrict__ w1,
    int* __restrict__ eid, float* __restrict__ alpha, int* __restrict__ counts,
    unsigned short* __restrict__ xln, unsigned short* __restrict__ w1t)
{
  __shared__ float T[2][64 * 64];
  __shared__ float part[4][NEXP], ps[4], pss[4];
  __shared__ float sMu, sRstd;
  __shared__ int sE;
  const int bid = blockIdx.x, tid = threadIdx.x;

  if (bid < NT) {
    const int t = bid;
    const float4 xv = ((const float4*)(x + (size_t)t * DIM))[tid];
    float acc[NEXP];
#pragma unroll
    for (int e = 0; e < NEXP; ++e) {
      const float4 cv = ((const float4*)(cent + (size_t)e * DIM))[tid];
      acc[e] = xv.x * cv.x + xv.y * cv.y + xv.z * cv.z + xv.w * cv.w;
    }
    float s = xv.x + xv.y + xv.z + xv.w;
    float ss = xv.x * xv.x + xv.y * xv.y + xv.z * xv.z + xv.w * xv.w;
#pragma unroll
    for (int off = 32; off > 0; off >>= 1) {
#pragma unroll
      for (int e = 0; e < NEXP; ++e) acc[e] += __shfl_down(acc[e], off);
      s += __shfl_down(s, off); ss += __shfl_down(ss, off);
    }
    const int lane = tid & 63, w = tid >> 6;
    if (lane == 0) {
#pragma unroll
      for (int e = 0; e < NEXP; ++e) part[w][e] = acc[e];
      ps[w] = s; pss[w] = ss;
    }
    __syncthreads();
    if (tid == 0) {
      int best = 0; float bv = -1e30f;
#pragma unroll
      for (int e = 0; e < NEXP; ++e) {
        float v = part[0][e] + part[1][e] + part[2][e] + part[3][e];
        if (v > bv) { bv = v; best = e; }   // strict >: first max (matches argmax)
      }
      eid[t] = best;
      alpha[t] = 1.0f / (1.0f + expf(-bv));
      atomicAdd(&counts[best], 1);
      const float sum = ps[0] + ps[1] + ps[2] + ps[3];
      const float sq  = pss[0] + pss[1] + pss[2] + pss[3];
      const float mu = sum * (1.0f / DIM);
      const float var = sq * (1.0f / DIM) - mu * mu;
      sE = best; sMu = mu; sRstd = rsqrtf(var + 1e-5f);
    }
    __syncthreads();
    const int e = sE;
    const float mu = sMu, rstd = sRstd;
    const float4 gv = ((const float4*)(g + (size_t)e * DIM))[tid];
    const float4 bv4 = ((const float4*)(b + (size_t)e * DIM))[tid];
    ushort4 o;
    o.x = f2bf((xv.x - mu) * rstd * gv.x + bv4.x);
    o.y = f2bf((xv.y - mu) * rstd * gv.y + bv4.y);
    o.z = f2bf((xv.z - mu) * rstd * gv.z + bv4.z);
    o.w = f2bf((xv.w - mu) * rstd * gv.w + bv4.w);
    ((ushort4*)(xln + (size_t)t * DIM))[tid] = o;
  } else {
    // w1 [E][D][F] -> w1t [E][F][D]; 16 r-tiles x 32 c-tile-PAIRS per expert
    const int i = bid - NT;                   // [0,4096)
    const int e = i >> 9, rem = i & 511;
    const float* src = w1 + (size_t)e * DIM * FDIM;
    unsigned short* dst = w1t + (size_t)e * DIM * FDIM;
    const int r0 = (rem & 15) * 64, c0 = (rem >> 4) * 128;
    tr64_issue(src, FDIM, r0, c0,      T[0], tid);
    tr64_issue(src, FDIM, r0, c0 + 64, T[1], tid);
    __syncthreads();                          // one drain for both tiles
    tr64_process(dst, DIM, r0, c0,      T[0], tid);
    tr64_process(dst, DIM, r0, c0 + 64, T[1], tid);
  }
}

// ---------------- exclusive scan of 8 counts ----------------
__global__ void k_scan(const int* __restrict__ counts, int* __restrict__ bs, int* __restrict__ cur) {
  if (threadIdx.x == 0) {
    int s = 0;
    for (int e = 0; e < NEXP; ++e) { bs[e] = s; cur[e] = s; s += counts[e]; }
  }
}

// ---------------- build pos -> token map (index-only counting sort) ----------------
__global__ void k_rowtok(const int* __restrict__ eid, int* __restrict__ cur,
                         int* __restrict__ row_tok) {
  const int t = blockIdx.x * 256 + threadIdx.x;
  const int e = eid[t];
  const int pos = atomicAdd(&cur[e], 1);
  row_tok[pos] = t;
}

// ---------------- GEMM1 (R12-proven 128x128) + appended w2-transpose (R19) ----
// bids [0,16384): grouped GEMM (e=bid&7==XCD, m fastest); [16384,24576): w2t
// 64x64 tiles — dispatched last, DMA hides under GEMM MFMA (R19: +3us).
__global__ __launch_bounds__(256) void k_gemm1(
    const unsigned short* __restrict__ A,
    const unsigned short* __restrict__ Bt,
    const float* __restrict__ bias,
    const int* __restrict__ bs, const int* __restrict__ counts,
    unsigned short* __restrict__ Hout,
    const int* __restrict__ row_tok,
    const float* __restrict__ w2, unsigned short* __restrict__ w2t)
{
  __shared__ __align__(16) char smem[32 * 132 * 4];
  const int tid = threadIdx.x;

  if (blockIdx.x >= 16384) {
    const int i = blockIdx.x - 16384, e = i >> 10, rem = i & 1023;
    float* T = (float*)smem;
    const float* src = w2 + (size_t)e * FDIM * DIM;
    unsigned short* dst = w2t + (size_t)e * FDIM * DIM;
    const int r0 = (rem >> 4) * 64, c0 = (rem & 15) * 64;
    tr64_issue(src, DIM, r0, c0, T, tid);
    __syncthreads();
    tr64_process(dst, FDIM, r0, c0, T, tid);
    return;
  }

  unsigned short* lA = (unsigned short*)smem;
  unsigned short* lB = (unsigned short*)(smem + 8192);
  float* Lf = (float*)smem;

  const int MB = NT / 128;
  const int bid = blockIdx.x;
  const int e = bid & 7;
  const int l = bid >> 3;
  const int m0 = (l % MB) * 128;               // m fastest
  const int cnt = counts[e];
  if (m0 >= cnt) return;
  const int n0 = (l / MB) * 128;
  const int rbase = bs[e];

  const int lane = tid & 63, wv = tid >> 6;
  const int wm = (wv >> 1) * 64, wn = (wv & 1) * 64;
  const int lr = lane & 15, lg = lane >> 4;

  fx4 acc[4][4] = {};

  const unsigned short* Bte = Bt + (size_t)e * (size_t)FDIM * DIM;

  const unsigned short* aP[2];
  const unsigned short* bP[2];
#pragma unroll
  for (int p = 0; p < 2; ++p) {
    const int g = p * 256 + tid;
    const int row = g >> 2, kq = (g & 3) * 8;
    int ar = rbase + m0 + row;
    ar = ar < NT ? ar : NT - 1;               // clamp: pad rows masked at epilogue
    const int tok = row_tok[ar];              // gather: xln is natural order
    aP[p] = A + (size_t)tok * DIM + kq;
    bP[p] = Bte + (size_t)(n0 + row) * DIM + kq;
  }

  for (int k0 = 0; k0 < DIM; k0 += 32) {
    gload16(aP[0] + k0, &lA[(0 * 4 + wv) * 512]);
    gload16(aP[1] + k0, &lA[(1 * 4 + wv) * 512]);
    gload16(bP[0] + k0, &lB[(0 * 4 + wv) * 512]);
    gload16(bP[1] + k0, &lB[(1 * 4 + wv) * 512]);
    __syncthreads();                          // compiler-managed vmcnt drain
    bfx8 bf[4];
#pragma unroll
    for (int j = 0; j < 4; ++j)
      bf[j] = *(const bfx8*)(&lB[(wn + j * 16 + lr) * 32 + lg * 8]);
#pragma unroll
    for (int i = 0; i < 4; ++i) {
      const bfx8 af = *(const bfx8*)(&lA[(wm + i * 16 + lr) * 32 + lg * 8]);
#pragma unroll
      for (int j = 0; j < 4; ++j)
        acc[i][j] = __builtin_amdgcn_mfma_f32_16x16x32_bf16(af, bf[j], acc[i][j], 0, 0, 0);
    }
    __syncthreads();
  }

  const float* be = bias + (size_t)e * FDIM;
  float bcol[4];
#pragma unroll
  for (int j = 0; j < 4; ++j) bcol[j] = be[n0 + wn + j * 16 + lr];

#pragma unroll
  for (int i = 0; i < 4; ++i) {
    __syncthreads();                          // protect LDS reuse
#pragma unroll
    for (int r2 = 0; r2 < 4; ++r2) {
      const int rowp = (wv >> 1) * 16 + lg * 4 + r2;    // 0..31
#pragma unroll
      for (int j = 0; j < 4; ++j) {
        float v = acc[i][j][r2] + bcol[j];
        Lf[rowp * 132 + wn + j * 16 + lr] = v > 0.f ? v : 0.f;
      }
    }
    __syncthreads();
#pragma unroll
    for (int s = 0; s < 2; ++s) {
      const int tsk = tid + 256 * s;                  // 0..511
      const int rr = tsk >> 4, cg = tsk & 15;
      const int ra = i * 16 + ((rr >> 4) << 6) + (rr & 15);
      if (m0 + ra < cnt) {
        const float4 a = *(const float4*)&Lf[rr * 132 + cg * 8];
        const float4 b = *(const float4*)&Lf[rr * 132 + cg * 8 + 4];
        unsigned short o[8] = { f2bf(a.x), f2bf(a.y), f2bf(a.z), f2bf(a.w),
                                f2bf(b.x), f2bf(b.y), f2bf(b.z), f2bf(b.w) };
        *(uint4*)(Hout + (size_t)(rbase + m0 + ra) * FDIM + n0 + cg * 8) =
            *(const uint4*)o;
      }
    }
  }
}

// ---------------- GEMM2: R17/R19 byte-identical ----------------
__global__ __launch_bounds__(256) void k_gemm2(
    const unsigned short* __restrict__ A,
    const unsigned short* __restrict__ Bt,
    const float* __restrict__ bias,
    const int* __restrict__ bs, const int* __restrict__ counts,
    const int* __restrict__ row_tok, const float* __restrict__ alpha,
    const float* __restrict__ xin, float* __restrict__ out)
{
  const int MB = NT / 128;
  const int bid = blockIdx.x;
  const int e = bid & 7;
  const int l = bid >> 3;
  const int m0 = (l % MB) * 128;               // m fastest
  const int cnt = counts[e];
  if (m0 >= cnt) return;
  const int n0 = (l / MB) * 128;
  const int rbase = bs[e];

  __shared__ __align__(16) char smem[32 * 132 * 4];
  unsigned short* lA = (unsigned short*)smem;
  unsigned short* lB = (unsigned short*)(smem + 8192);
  float* Lf = (float*)smem;

  const int tid = threadIdx.x;
  const int lane = tid & 63, wv = tid >> 6;
  const int wm = (wv >> 1) * 64, wn = (wv & 1) * 64;
  const int lr = lane & 15, lg = lane >> 4;

  fx4 acc[4][4] = {};

  const unsigned short* Bte = Bt + (size_t)e * (size_t)DIM * FDIM;

  const unsigned short* aP[2];
  const unsigned short* bP[2];
#pragma unroll
  for (int p = 0; p < 2; ++p) {
    const int g = p * 256 + tid;
    const int row = g >> 2, kq = (g & 3) * 8;
    int ar = rbase + m0 + row;
    ar = ar < NT ? ar : NT - 1;               // clamp: pad rows masked at epilogue
    aP[p] = A + (size_t)ar * FDIM + kq;       // hbuf is sorted order
    bP[p] = Bte + (size_t)(n0 + row) * FDIM + kq;
  }

  for (int k0 = 0; k0 < FDIM; k0 += 32) {
    gload16(aP[0] + k0, &lA[(0 * 4 + wv) * 512]);
    gload16(aP[1] + k0, &lA[(1 * 4 + wv) * 512]);
    gload16(bP[0] + k0, &lB[(0 * 4 + wv) * 512]);
    gload16(bP[1] + k0, &lB[(1 * 4 + wv) * 512]);
    __syncthreads();                          // compiler-managed vmcnt drain
    bfx8 bf[4];
#pragma unroll
    for (int j = 0; j < 4; ++j)
      bf[j] = *(const bfx8*)(&lB[(wn + j * 16 + lr) * 32 + lg * 8]);
#pragma unroll
    for (int i = 0; i < 4; ++i) {
      const bfx8 af = *(const bfx8*)(&lA[(wm + i * 16 + lr) * 32 + lg * 8]);
#pragma unroll
      for (int j = 0; j < 4; ++j)
        acc[i][j] = __builtin_amdgcn_mfma_f32_16x16x32_bf16(af, bf[j], acc[i][j], 0, 0, 0);
    }
    __syncthreads();
  }

  const float* be = bias + (size_t)e * DIM;
  float bcol[4];
#pragma unroll
  for (int j = 0; j < 4; ++j) bcol[j] = be[n0 + wn + j * 16 + lr];

#pragma unroll
  for (int i = 0; i < 4; ++i) {
    __syncthreads();                          // protect LDS reuse
#pragma unroll
    for (int r2 = 0; r2 < 4; ++r2) {
      const int rowp = (wv >> 1) * 16 + lg * 4 + r2;    // 0..31
#pragma unroll
      for (int j = 0; j < 4; ++j)
        Lf[rowp * 132 + wn + j * 16 + lr] = acc[i][j][r2] + bcol[j];
    }
    __syncthreads();
#pragma unroll
    for (int s = 0; s < 4; ++s) {
      const int tsk = tid + 256 * s;                  // 0..1023
      const int rr = tsk >> 5, c4 = tsk & 31;
      const int ra = i * 16 + ((rr >> 4) << 6) + (rr & 15);
      if (m0 + ra < cnt) {
        const int tok = row_tok[rbase + m0 + ra];
        const float al = alpha[tok];
        const float4 v = *(const float4*)&Lf[rr * 132 + c4 * 4];
        const float4 xr = *(const float4*)(xin + (size_t)tok * DIM + n0 + c4 * 4);
        float4 o;
        o.x = xr.x + al * v.x;
        o.y = xr.y + al * v.y;
        o.z = xr.z + al * v.z;
        o.w = xr.w + al * v.w;
        *(float4*)(out + (size_t)tok * DIM + n0 + c4 * 4) = o;
      }
    }
  }
}

extern "C" void kernel_launch(void* const* d_in, const int* in_sizes, int n_in,
                              void* d_out, int out_size, void* d_ws, size_t ws_size,
                              hipStream_t stream)
{
  const float* x    = (const float*)d_in[0];
  const float* cent = (const float*)d_in[1];
  const float* ln_g = (const float*)d_in[2];
  const float* ln_b = (const float*)d_in[3];
  const float* w1   = (const float*)d_in[4];
  const float* b1   = (const float*)d_in[5];
  const float* w2   = (const float*)d_in[6];
  const float* b2   = (const float*)d_in[7];
  float* out = (float*)d_out;

  char* ws = (char*)d_ws;
  unsigned short* xln  = (unsigned short*)(ws);                          // 16 MB (natural order)
  unsigned short* hbuf = (unsigned short*)(ws + (16ull << 20));          // 64 MB (sorted order)
  unsigned short* w1t  = (unsigned short*)(ws + (80ull << 20));          // 64 MB [E][F][D]
  unsigned short* w2t  = (unsigned short*)(ws + (144ull << 20));         // 64 MB [E][D][F]
  char* tail = ws + (208ull << 20);
  int*    eid    = (int*)(tail);
  float*  alpha  = (float*)(tail + 32768);
  int*    rowtok = (int*)(tail + 65536);
  int*    counts = (int*)(tail + 98304);
  int*    basep  = counts + 16;
  int*    cur    = counts + 32;

  k_zero<<<1, 64, 0, stream>>>(counts);
  k_pre<<<NT + 4096, 256, 0, stream>>>(
      x, cent, ln_g, ln_b, w1, eid, alpha, counts, xln, w1t);
  k_scan<<<1, 1, 0, stream>>>(counts, basep, cur);
  k_rowtok<<<NT / 256, 256, 0, stream>>>(eid, cur, rowtok);
  k_gemm1<<<16384 + 8192, 256, 0, stream>>>(
      xln, w1t, b1, basep, counts, hbuf, rowtok, w2, w2t);
  k_gemm2<<<NEXP * (NT / 128) * (DIM / 128), 256, 0, stream>>>(
      hbuf, w2t, b2, basep, counts, rowtok, alpha, x, out);
}

// Round 22
// 412.243 us; speedup vs baseline: 1.0550x; 1.0366x over previous
//
#include <hip/hip_runtime.h>

#define NT 8192      // tokens = B*S
#define DIM 1024     // D
#define FDIM 4096    // F
#define NEXP 8       // experts

typedef __attribute__((ext_vector_type(8))) short bfx8;   // 8 bf16 (4 VGPRs)
typedef __attribute__((ext_vector_type(4))) float fx4;    // MFMA accumulator

__device__ __forceinline__ unsigned short f2bf(float f) {
  union { float f; unsigned u; } v; v.f = f;
  unsigned u = v.u;
  unsigned r = u + 0x7FFFu + ((u >> 16) & 1u);   // round-to-nearest-even
  return (unsigned short)(r >> 16);
}

__device__ __forceinline__ void gload16(const void* g, void* l) {
  __builtin_amdgcn_global_load_lds(
      (const __attribute__((address_space(1))) unsigned int*)g,
      (__attribute__((address_space(3))) unsigned int*)l, 16, 0, 0);
}

// ---- 64x64 transpose tile, two-key swizzle (R18/R19-proven) ----
__device__ __forceinline__ void tr64_issue(
    const float* __restrict__ src, int C, int r0, int c0, float* T, int tid)
{
  const int lane = tid & 63, wv = tid >> 6;
  const int rw = wv * 4 + (lane >> 4);          // row within each 16-row group
#pragma unroll
  for (int i = 0; i < 4; ++i) {
    const int cb = (lane & 15) ^ (rw & 7) ^ (i * 2) ^ (rw >> 3);
    gload16(src + (size_t)(r0 + i * 16 + rw) * C + c0 + cb * 4,
            &T[(i * 16 + wv * 4) * 64]);
  }
}

__device__ __forceinline__ void tr64_process(
    unsigned short* __restrict__ dst, int R, int r0, int c0, const float* T, int tid)
{
  const int q = tid & 7, cy = tid >> 3;
#pragma unroll
  for (int it = 0; it < 2; ++it) {
    const int c = cy + it * 32;
    unsigned short o[8];
#pragma unroll
    for (int u = 0; u < 8; ++u)
      o[u] = f2bf(T[(q * 8 + u) * 64 + ((((c >> 2) ^ u ^ q) << 2) | (c & 3))]);
    *(uint4*)(dst + (size_t)(c0 + c) * R + r0 + q * 8) = *(const uint4*)o;
  }
}

// ---------------- zero counters ----------------
__global__ void k_zero(int* __restrict__ counts) {
  if (threadIdx.x < NEXP) counts[threadIdx.x] = 0;
}

// ---------------- P1: routing+LN AND one w1^T tile per block (merged 1:1) ----
// 8192 blocks. Each block: (a) issue its w1t tile's 4 DMAs, (b) routing+LN for
// token bid (its loads/compute cover the DMA latency; routing's barriers drain
// vmcnt -> T ready), (c) process the transpose. Block-level heterogeneous
// overlap — same mechanism as R19's appended-w2t (+3us for 8192 tiles).
__global__ __launch_bounds__(256) void k_pre(
    const float* __restrict__ x, const float* __restrict__ cent,
    const float* __restrict__ g, const float* __restrict__ b,
    const float* __restrict__ w1,
    int* __restrict__ eid, float* __restrict__ alpha, int* __restrict__ counts,
    unsigned short* __restrict__ xln, unsigned short* __restrict__ w1t)
{
  __shared__ float T[64 * 64];
  __shared__ float part[4][NEXP], ps[4], pss[4];
  __shared__ float sMu, sRstd;
  __shared__ int sE;
  const int bid = blockIdx.x, tid = threadIdx.x;

  // (a) transpose tile DMAs first (in flight alongside routing's loads)
  const int te = bid >> 10, trem = bid & 1023;
  const int tr0 = (trem & 15) * 64, tc0 = (trem >> 4) * 64;
  const float* tsrc = w1 + (size_t)te * DIM * FDIM;
  tr64_issue(tsrc, FDIM, tr0, tc0, T, tid);

  // (b) routing + LN for token bid
  const int t = bid;
  const float4 xv = ((const float4*)(x + (size_t)t * DIM))[tid];
  float acc[NEXP];
#pragma unroll
  for (int e = 0; e < NEXP; ++e) {
    const float4 cv = ((const float4*)(cent + (size_t)e * DIM))[tid];
    acc[e] = xv.x * cv.x + xv.y * cv.y + xv.z * cv.z + xv.w * cv.w;
  }
  float s = xv.x + xv.y + xv.z + xv.w;
  float ss = xv.x * xv.x + xv.y * xv.y + xv.z * xv.z + xv.w * xv.w;
#pragma unroll
  for (int off = 32; off > 0; off >>= 1) {
#pragma unroll
    for (int e = 0; e < NEXP; ++e) acc[e] += __shfl_down(acc[e], off);
    s += __shfl_down(s, off); ss += __shfl_down(ss, off);
  }
  const int lane = tid & 63, w = tid >> 6;
  if (lane == 0) {
#pragma unroll
    for (int e = 0; e < NEXP; ++e) part[w][e] = acc[e];
    ps[w] = s; pss[w] = ss;
  }
  __syncthreads();
  if (tid == 0) {
    int best = 0; float bv = -1e30f;
#pragma unroll
    for (int e = 0; e < NEXP; ++e) {
      float v = part[0][e] + part[1][e] + part[2][e] + part[3][e];
      if (v > bv) { bv = v; best = e; }   // strict >: first max (matches argmax)
    }
    eid[t] = best;
    alpha[t] = 1.0f / (1.0f + expf(-bv));
    atomicAdd(&counts[best], 1);
    const float sum = ps[0] + ps[1] + ps[2] + ps[3];
    const float sq  = pss[0] + pss[1] + pss[2] + pss[3];
    const float mu = sum * (1.0f / DIM);
    const float var = sq * (1.0f / DIM) - mu * mu;
    sE = best; sMu = mu; sRstd = rsqrtf(var + 1e-5f);
  }
  __syncthreads();                             // also guarantees DMAs landed
  const int e = sE;
  const float mu = sMu, rstd = sRstd;
  const float4 gv = ((const float4*)(g + (size_t)e * DIM))[tid];
  const float4 bv4 = ((const float4*)(b + (size_t)e * DIM))[tid];
  ushort4 o;
  o.x = f2bf((xv.x - mu) * rstd * gv.x + bv4.x);
  o.y = f2bf((xv.y - mu) * rstd * gv.y + bv4.y);
  o.z = f2bf((xv.z - mu) * rstd * gv.z + bv4.z);
  o.w = f2bf((xv.w - mu) * rstd * gv.w + bv4.w);
  ((ushort4*)(xln + (size_t)t * DIM))[tid] = o;

  // (c) process the transpose tile (T guaranteed complete)
  tr64_process(w1t + (size_t)te * DIM * FDIM, DIM, tr0, tc0, T, tid);
}

// ---------------- exclusive scan of 8 counts ----------------
__global__ void k_scan(const int* __restrict__ counts, int* __restrict__ bs, int* __restrict__ cur) {
  if (threadIdx.x == 0) {
    int s = 0;
    for (int e = 0; e < NEXP; ++e) { bs[e] = s; cur[e] = s; s += counts[e]; }
  }
}

// ---------------- build pos -> token map (index-only counting sort) ----------------
__global__ void k_rowtok(const int* __restrict__ eid, int* __restrict__ cur,
                         int* __restrict__ row_tok) {
  const int t = blockIdx.x * 256 + threadIdx.x;
  const int e = eid[t];
  const int pos = atomicAdd(&cur[e], 1);
  row_tok[pos] = t;
}

// ---------------- GEMM1 (R12-proven 128x128) + appended w2-transpose (R19) ----
__global__ __launch_bounds__(256) void k_gemm1(
    const unsigned short* __restrict__ A,
    const unsigned short* __restrict__ Bt,
    const float* __restrict__ bias,
    const int* __restrict__ bs, const int* __restrict__ counts,
    unsigned short* __restrict__ Hout,
    const int* __restrict__ row_tok,
    const float* __restrict__ w2, unsigned short* __restrict__ w2t)
{
  __shared__ __align__(16) char smem[32 * 132 * 4];
  const int tid = threadIdx.x;

  if (blockIdx.x >= 16384) {
    const int i = blockIdx.x - 16384, e = i >> 10, rem = i & 1023;
    float* T = (float*)smem;
    const float* src = w2 + (size_t)e * FDIM * DIM;
    unsigned short* dst = w2t + (size_t)e * FDIM * DIM;
    const int r0 = (rem >> 4) * 64, c0 = (rem & 15) * 64;
    tr64_issue(src, DIM, r0, c0, T, tid);
    __syncthreads();
    tr64_process(dst, FDIM, r0, c0, T, tid);
    return;
  }

  unsigned short* lA = (unsigned short*)smem;
  unsigned short* lB = (unsigned short*)(smem + 8192);
  float* Lf = (float*)smem;

  const int MB = NT / 128;
  const int bid = blockIdx.x;
  const int e = bid & 7;
  const int l = bid >> 3;
  const int m0 = (l % MB) * 128;               // m fastest
  const int cnt = counts[e];
  if (m0 >= cnt) return;
  const int n0 = (l / MB) * 128;
  const int rbase = bs[e];

  const int lane = tid & 63, wv = tid >> 6;
  const int wm = (wv >> 1) * 64, wn = (wv & 1) * 64;
  const int lr = lane & 15, lg = lane >> 4;

  fx4 acc[4][4] = {};

  const unsigned short* Bte = Bt + (size_t)e * (size_t)FDIM * DIM;

  const unsigned short* aP[2];
  const unsigned short* bP[2];
#pragma unroll
  for (int p = 0; p < 2; ++p) {
    const int g = p * 256 + tid;
    const int row = g >> 2, kq = (g & 3) * 8;
    int ar = rbase + m0 + row;
    ar = ar < NT ? ar : NT - 1;               // clamp: pad rows masked at epilogue
    const int tok = row_tok[ar];              // gather: xln is natural order
    aP[p] = A + (size_t)tok * DIM + kq;
    bP[p] = Bte + (size_t)(n0 + row) * DIM + kq;
  }

  for (int k0 = 0; k0 < DIM; k0 += 32) {
    gload16(aP[0] + k0, &lA[(0 * 4 + wv) * 512]);
    gload16(aP[1] + k0, &lA[(1 * 4 + wv) * 512]);
    gload16(bP[0] + k0, &lB[(0 * 4 + wv) * 512]);
    gload16(bP[1] + k0, &lB[(1 * 4 + wv) * 512]);
    __syncthreads();                          // compiler-managed vmcnt drain
    bfx8 bf[4];
#pragma unroll
    for (int j = 0; j < 4; ++j)
      bf[j] = *(const bfx8*)(&lB[(wn + j * 16 + lr) * 32 + lg * 8]);
#pragma unroll
    for (int i = 0; i < 4; ++i) {
      const bfx8 af = *(const bfx8*)(&lA[(wm + i * 16 + lr) * 32 + lg * 8]);
#pragma unroll
      for (int j = 0; j < 4; ++j)
        acc[i][j] = __builtin_amdgcn_mfma_f32_16x16x32_bf16(af, bf[j], acc[i][j], 0, 0, 0);
    }
    __syncthreads();
  }

  const float* be = bias + (size_t)e * FDIM;
  float bcol[4];
#pragma unroll
  for (int j = 0; j < 4; ++j) bcol[j] = be[n0 + wn + j * 16 + lr];

#pragma unroll
  for (int i = 0; i < 4; ++i) {
    __syncthreads();                          // protect LDS reuse
#pragma unroll
    for (int r2 = 0; r2 < 4; ++r2) {
      const int rowp = (wv >> 1) * 16 + lg * 4 + r2;    // 0..31
#pragma unroll
      for (int j = 0; j < 4; ++j) {
        float v = acc[i][j][r2] + bcol[j];
        Lf[rowp * 132 + wn + j * 16 + lr] = v > 0.f ? v : 0.f;
      }
    }
    __syncthreads();
#pragma unroll
    for (int s = 0; s < 2; ++s) {
      const int tsk = tid + 256 * s;                  // 0..511
      const int rr = tsk >> 4, cg = tsk & 15;
      const int ra = i * 16 + ((rr >> 4) << 6) + (rr & 15);
      if (m0 + ra < cnt) {
        const float4 a = *(const float4*)&Lf[rr * 132 + cg * 8];
        const float4 b = *(const float4*)&Lf[rr * 132 + cg * 8 + 4];
        unsigned short o[8] = { f2bf(a.x), f2bf(a.y), f2bf(a.z), f2bf(a.w),
                                f2bf(b.x), f2bf(b.y), f2bf(b.z), f2bf(b.w) };
        *(uint4*)(Hout + (size_t)(rbase + m0 + ra) * FDIM + n0 + cg * 8) =
            *(const uint4*)o;
      }
    }
  }
}

// ---------------- GEMM2: R17/R19/R21 byte-identical ----------------
__global__ __launch_bounds__(256) void k_gemm2(
    const unsigned short* __restrict__ A,
    const unsigned short* __restrict__ Bt,
    const float* __restrict__ bias,
    const int* __restrict__ bs, const int* __restrict__ counts,
    const int* __restrict__ row_tok, const float* __restrict__ alpha,
    const float* __restrict__ xin, float* __restrict__ out)
{
  const int MB = NT / 128;
  const int bid = blockIdx.x;
  const int e = bid & 7;
  const int l = bid >> 3;
  const int m0 = (l % MB) * 128;               // m fastest
  const int cnt = counts[e];
  if (m0 >= cnt) return;
  const int n0 = (l / MB) * 128;
  const int rbase = bs[e];

  __shared__ __align__(16) char smem[32 * 132 * 4];
  unsigned short* lA = (unsigned short*)smem;
  unsigned short* lB = (unsigned short*)(smem + 8192);
  float* Lf = (float*)smem;

  const int tid = threadIdx.x;
  const int lane = tid & 63, wv = tid >> 6;
  const int wm = (wv >> 1) * 64, wn = (wv & 1) * 64;
  const int lr = lane & 15, lg = lane >> 4;

  fx4 acc[4][4] = {};

  const unsigned short* Bte = Bt + (size_t)e * (size_t)DIM * FDIM;

  const unsigned short* aP[2];
  const unsigned short* bP[2];
#pragma unroll
  for (int p = 0; p < 2; ++p) {
    const int g = p * 256 + tid;
    const int row = g >> 2, kq = (g & 3) * 8;
    int ar = rbase + m0 + row;
    ar = ar < NT ? ar : NT - 1;               // clamp: pad rows masked at epilogue
    aP[p] = A + (size_t)ar * FDIM + kq;       // hbuf is sorted order
    bP[p] = Bte + (size_t)(n0 + row) * FDIM + kq;
  }

  for (int k0 = 0; k0 < FDIM; k0 += 32) {
    gload16(aP[0] + k0, &lA[(0 * 4 + wv) * 512]);
    gload16(aP[1] + k0, &lA[(1 * 4 + wv) * 512]);
    gload16(bP[0] + k0, &lB[(0 * 4 + wv) * 512]);
    gload16(bP[1] + k0, &lB[(1 * 4 + wv) * 512]);
    __syncthreads();                          // compiler-managed vmcnt drain
    bfx8 bf[4];
#pragma unroll
    for (int j = 0; j < 4; ++j)
      bf[j] = *(const bfx8*)(&lB[(wn + j * 16 + lr) * 32 + lg * 8]);
#pragma unroll
    for (int i = 0; i < 4; ++i) {
      const bfx8 af = *(const bfx8*)(&lA[(wm + i * 16 + lr) * 32 + lg * 8]);
#pragma unroll
      for (int j = 0; j < 4; ++j)
        acc[i][j] = __builtin_amdgcn_mfma_f32_16x16x32_bf16(af, bf[j], acc[i][j], 0, 0, 0);
    }
    __syncthreads();
  }

  const float* be = bias + (size_t)e * DIM;
  float bcol[4];
#pragma unroll
  for (int j = 0; j < 4; ++j) bcol[j] = be[n0 + wn + j * 16 + lr];

#pragma unroll
  for (int i = 0; i < 4; ++i) {
    __syncthreads();                          // protect LDS reuse
#pragma unroll
    for (int r2 = 0; r2 < 4; ++r2) {
      const int rowp = (wv >> 1) * 16 + lg * 4 + r2;    // 0..31
#pragma unroll
      for (int j = 0; j < 4; ++j)
        Lf[rowp * 132 + wn + j * 16 + lr] = acc[i][j][r2] + bcol[j];
    }
    __syncthreads();
#pragma unroll
    for (int s = 0; s < 4; ++s) {
      const int tsk = tid + 256 * s;                  // 0..1023
      const int rr = tsk >> 5, c4 = tsk & 31;
      const int ra = i * 16 + ((rr >> 4) << 6) + (rr & 15);
      if (m0 + ra < cnt) {
        const int tok = row_tok[rbase + m0 + ra];
        const float al = alpha[tok];
        const float4 v = *(const float4*)&Lf[rr * 132 + c4 * 4];
        const float4 xr = *(const float4*)(xin + (size_t)tok * DIM + n0 + c4 * 4);
        float4 o;
        o.x = xr.x + al * v.x;
        o.y = xr.y + al * v.y;
        o.z = xr.z + al * v.z;
        o.w = xr.w + al * v.w;
        *(float4*)(out + (size_t)tok * DIM + n0 + c4 * 4) = o;
      }
    }
  }
}

extern "C" void kernel_launch(void* const* d_in, const int* in_sizes, int n_in,
                              void* d_out, int out_size, void* d_ws, size_t ws_size,
                              hipStream_t stream)
{
  const float* x    = (const float*)d_in[0];
  const float* cent = (const float*)d_in[1];
  const float* ln_g = (const float*)d_in[2];
  const float* ln_b = (const float*)d_in[3];
  const float* w1   = (const float*)d_in[4];
  const float* b1   = (const float*)d_in[5];
  const float* w2   = (const float*)d_in[6];
  const float* b2   = (const float*)d_in[7];
  float* out = (float*)d_out;

  char* ws = (char*)d_ws;
  unsigned short* xln  = (unsigned short*)(ws);                          // 16 MB (natural order)
  unsigned short* hbuf = (unsigned short*)(ws + (16ull << 20));          // 64 MB (sorted order)
  unsigned short* w1t  = (unsigned short*)(ws + (80ull << 20));          // 64 MB [E][F][D]
  unsigned short* w2t  = (unsigned short*)(ws + (144ull << 20));         // 64 MB [E][D][F]
  char* tail = ws + (208ull << 20);
  int*    eid    = (int*)(tail);
  float*  alpha  = (float*)(tail + 32768);
  int*    rowtok = (int*)(tail + 65536);
  int*    counts = (int*)(tail + 98304);
  int*    basep  = counts + 16;
  int*    cur    = counts + 32;

  k_zero<<<1, 64, 0, stream>>>(counts);
  k_pre<<<NT, 256, 0, stream>>>(
      x, cent, ln_g, ln_b, w1, eid, alpha, counts, xln, w1t);
  k_scan<<<1, 1, 0, stream>>>(counts, basep, cur);
  k_rowtok<<<NT / 256, 256, 0, stream>>>(eid, cur, rowtok);
  k_gemm1<<<16384 + 8192, 256, 0, stream>>>(
      xln, w1t, b1, basep, counts, hbuf, rowtok, w2, w2t);
  k_gemm2<<<NEXP * (NT / 128) * (DIM / 128), 256, 0, stream>>>(
      hbuf, w2t, b2, basep, counts, rowtok, alpha, x, out);
}